// Round 10
// baseline (103.662 us; speedup 1.0000x reference)
//
#include <hip/hip_runtime.h>
#include <math.h>

#define B_N 65536
#define C_N 100
#define NELEM (B_N * C_N)          // 6,553,600
constexpr float ALPHA = 0.01f;
constexpr float TAU   = 2.0f;
constexpr float TEMP  = 2.0f;
constexpr float EPSF  = 1e-9f;

// ---------------- full-wave (64-lane) DPP sum: result valid on lanes 48..63 ----------------
template<int CTRL>
__device__ __forceinline__ float fadd_dpp(float x) {
    return x + __int_as_float(__builtin_amdgcn_update_dpp(
        0, __float_as_int(x), CTRL, 0xF, 0xF, true));
}
__device__ __forceinline__ float dppsum64(float x) {
    x = fadd_dpp<0xB1>(x);    // quad_perm xor1
    x = fadd_dpp<0x4E>(x);    // quad_perm xor2
    x = fadd_dpp<0x124>(x);   // row_ror:4
    x = fadd_dpp<0x128>(x);   // row_ror:8
    x = fadd_dpp<0x142>(x);   // row_bcast15 -> 32-group totals in (lane&31)>=16
    x = fadd_dpp<0x143>(x);   // row_bcast31 -> full-wave total in lanes 48..63
    return x;
}
__device__ __forceinline__ unsigned long long wmax64(unsigned long long k) {
    #pragma unroll
    for (int o = 32; o; o >>= 1) {
        const unsigned long long t = __shfl_xor(k, o);
        k = (t > k) ? t : k;
    }
    return k;
}
__device__ __forceinline__ float wsum(float v) {
    #pragma unroll
    for (int o = 32; o; o >>= 1) v += __shfl_xor(v, o);
    return v;
}
__device__ __forceinline__ unsigned div100(unsigned n) {
    return __umulhi(n, 0x51EB851Fu) >> 5;    // Hacker's Delight magic for /100
}

// ---------- prep: bincount (0-255) + prior tables (256) + cos softmax (257-260) ----------
__global__ void prep_k(const float* __restrict__ cosf, const float* __restrict__ prior,
                       const int* __restrict__ target,
                       float* __restrict__ sm, float* __restrict__ w2,
                       float* __restrict__ w3, float* __restrict__ Ht,
                       int* __restrict__ counts) {
    const int b = blockIdx.x;
    if (b < 256) {
        __shared__ int h[C_N];
        for (int i = threadIdx.x; i < C_N; i += blockDim.x) h[i] = 0;
        __syncthreads();
        const int gid = b * blockDim.x + threadIdx.x;
        const int stride = 256 * blockDim.x;
        for (int i = gid; i < B_N; i += stride) atomicAdd(&h[target[i]], 1);
        __syncthreads();
        for (int i = threadIdx.x; i < C_N; i += blockDim.x)
            if (h[i]) atomicAdd(&counts[i], h[i]);
    } else if (b == 256) {
        __shared__ float sp[C_N];
        __shared__ float val[C_N];
        const int t = threadIdx.x;
        if (t < C_N) sp[t] = prior[t];
        __syncthreads();
        int rank = 0;
        float lpi = 0.f, pi = 0.f;
        if (t < C_N) {
            pi = sp[t];
            for (int j = 0; j < C_N; ++j) {
                const float pj = sp[j];
                rank += (pj < pi) || (pj == pi && j < t);   // stable argsort rank
            }
            val[rank] = pi;
            lpi = __logf(pi + EPSF);
        }
        __syncthreads();
        if (t < C_N) {
            const float inv = val[C_N - 1 - rank];
            const float c3v = lpi - TAU * __logf(inv + EPSF);
            w2[t] = pi + EPSF;          // exp(e2+lp) = w2*exp(e2)
            w3[t] = __expf(c3v);        // exp(e3+c3) = w3*exp(e3)
            Ht[t] = lpi + c3v;          // lp+c3, for the label dot
        }
    } else {
        const int gw = (b - 257) * 4 + (threadIdx.x >> 6);   // 0..15
        const int lane = threadIdx.x & 63;
        for (int row = gw; row < C_N; row += 16) {
            const float* rp = cosf + row * C_N;
            const float v0 = rp[lane];
            const bool has1 = (lane + 64) < C_N;
            const float v1 = has1 ? rp[lane + 64] : -INFINITY;
            float m = fmaxf(v0, v1);
            #pragma unroll
            for (int o = 32; o; o >>= 1) m = fmaxf(m, __shfl_xor(m, o));
            const float e0 = __expf(v0 - m);
            const float e1 = has1 ? __expf(v1 - m) : 0.f;
            const float s = wsum(e0 + e1);
            const float is = 1.0f / s;
            sm[row * C_N + lane] = e0 * is;
            if (has1) sm[row * C_N + lane + 64] = e1 * is;
        }
    }
}

// ---------- CE: flat stream over e1,e2,e3; segmented wave sums -> atomics ----------
#define CTPB 256
#define CBLK (NELEM / CTPB)    // 25600

__launch_bounds__(CTPB)
__global__ void ce_k(const float* __restrict__ e1p, const float* __restrict__ e2p,
                     const float* __restrict__ e3p, const int* __restrict__ target,
                     const float* __restrict__ sm, const float* __restrict__ w2p,
                     const float* __restrict__ w3p, const float* __restrict__ Hp,
                     float* __restrict__ S1, float* __restrict__ S2,
                     float* __restrict__ S3, float* __restrict__ DT) {
    const int i = blockIdx.x * CTPB + threadIdx.x;
    const int lane = threadIdx.x & 63;
    const unsigned r = div100((unsigned)i);
    const int col = i - (int)r * C_N;

    const float v1 = e1p[i];
    const float v2 = e2p[i];
    const float v3 = e3p[i];
    const int tgt = target[r];
    const float smv = sm[tgt * C_N + col];
    const float h   = Hp[col];
    const float w2v = w2p[col];
    const float w3v = w3p[col];

    const float lab = ALPHA * smv + ((col == tgt) ? (1.0f - ALPHA) : 0.0f);
    const float q1 = __expf(v1);
    const float q2 = w2v * __expf(v2);
    const float q3 = w3v * __expf(v3);
    const float qd = lab * (v1 + v2 + v3 + h);

    const unsigned rlo = (unsigned)__shfl((int)r, 0);
    const unsigned rhi = (unsigned)__shfl((int)r, 63);
    const bool isA = (r == rlo);

    const float a1 = dppsum64(isA ? q1 : 0.f), b1 = dppsum64(isA ? 0.f : q1);
    const float a2 = dppsum64(isA ? q2 : 0.f), b2 = dppsum64(isA ? 0.f : q2);
    const float a3 = dppsum64(isA ? q3 : 0.f), b3 = dppsum64(isA ? 0.f : q3);
    const float ad = dppsum64(isA ? qd : 0.f), bd = dppsum64(isA ? 0.f : qd);

    if (lane == 63) {
        atomicAdd(&S1[rlo], a1);
        atomicAdd(&S2[rlo], a2);
        atomicAdd(&S3[rlo], a3);
        atomicAdd(&DT[rlo], ad);
        if (rhi != rlo) {
            atomicAdd(&S1[rhi], b1);
            atomicAdd(&S2[rhi], b2);
            atomicAdd(&S3[rhi], b3);
            atomicAdd(&DT[rhi], bd);
        }
    }
}

// ---------- TS: flat stream over old_pred,output; KL partials + argmax key + dout ----------
__launch_bounds__(CTPB)
__global__ void ts_k(const int* __restrict__ target,
                     const float* __restrict__ opp, const float* __restrict__ oup,
                     const int* __restrict__ cnts, float* __restrict__ dout,
                     float* __restrict__ ZT, float* __restrict__ ZS,
                     float* __restrict__ DD, unsigned long long* __restrict__ KEY) {
    const int i = blockIdx.x * CTPB + threadIdx.x;
    const int lane = threadIdx.x & 63;
    const unsigned r = div100((unsigned)i);
    const int col = i - (int)r * C_N;

    const float op = opp[i];
    const float ou = oup[i];
    const int tgt = target[r];
    const float rc = 1.0f / (float)cnts[tgt];
    const float es = ou * rc;
    dout[2 + i] = es;

    const float a = 0.5f * op;
    const float x = 0.5f * es;
    const float p = __expf(a);
    const float q = __expf(x);
    const float d = p * (a - x);

    unsigned bb = __float_as_uint(op);
    bb = ((int)bb < 0) ? ~bb : (bb | 0x80000000u);
    const unsigned long long key =
        ((unsigned long long)bb << 32) | (unsigned)(~col);   // max -> max val, then min col

    const unsigned rlo = (unsigned)__shfl((int)r, 0);
    const unsigned rhi = (unsigned)__shfl((int)r, 63);
    const bool isA = (r == rlo);

    const float azt = dppsum64(isA ? p : 0.f), bzt = dppsum64(isA ? 0.f : p);
    const float azs = dppsum64(isA ? q : 0.f), bzs = dppsum64(isA ? 0.f : q);
    const float add = dppsum64(isA ? d : 0.f), bdd = dppsum64(isA ? 0.f : d);
    const unsigned long long kA = wmax64(isA ? key : 0ull);
    const unsigned long long kB = wmax64(isA ? 0ull : key);

    if (lane == 63) {
        atomicAdd(&ZT[rlo], azt);
        atomicAdd(&ZS[rlo], azs);
        atomicAdd(&DD[rlo], add);
        atomicMax(&KEY[rlo], kA);
        if (rhi != rlo) {
            atomicAdd(&ZT[rhi], bzt);
            atomicAdd(&ZS[rhi], bzs);
            atomicAdd(&DD[rhi], bdd);
            atomicMax(&KEY[rhi], kB);
        }
    }
}

// ---------- row finish: ce + masked kl per row -> per-block partials ----------
__global__ void rf_k(const int* __restrict__ target,
                     const float* __restrict__ S1, const float* __restrict__ S2,
                     const float* __restrict__ S3, const float* __restrict__ DT,
                     const float* __restrict__ ZT, const float* __restrict__ ZS,
                     const float* __restrict__ DD, const unsigned long long* __restrict__ KEY,
                     float* __restrict__ pl, float* __restrict__ pk, float* __restrict__ pn) {
    const int t = threadIdx.x;
    const int row = blockIdx.x * 256 + t;
    const float s1 = S1[row], s2 = S2[row], s3 = S3[row], dt = DT[row];
    const float zt = ZT[row], zs = ZS[row], dd = DD[row];
    const unsigned long long key = KEY[row];
    const int mi = (int)(~(unsigned)key);          // recover col from ~col
    const int tgt = target[row];

    const float ce  = __logf(s1 * s2 * s3) - dt;
    const float rzt = 1.0f / zt;
    const float kl  = dd * rzt + __logf(zs * rzt);
    const bool  sel = (mi == tgt);

    __shared__ float sl[256], sk[256], sn[256];
    sl[t] = ce;
    sk[t] = sel ? kl : 0.f;
    sn[t] = sel ? 1.f : 0.f;
    __syncthreads();
    for (int s = 128; s; s >>= 1) {
        if (t < s) { sl[t] += sl[t + s]; sk[t] += sk[t + s]; sn[t] += sn[t + s]; }
        __syncthreads();
    }
    if (t == 0) { pl[blockIdx.x] = sl[0]; pk[blockIdx.x] = sk[0]; pn[blockIdx.x] = sn[0]; }
}

// ---------- final scalar reduce ----------
__global__ void f2_k(const float* __restrict__ pl, const float* __restrict__ pk,
                     const float* __restrict__ pn, float* __restrict__ dout) {
    __shared__ float sl[256], sk[256], sn[256];
    const int t = threadIdx.x;
    sl[t] = pl[t]; sk[t] = pk[t]; sn[t] = pn[t];
    __syncthreads();
    for (int s = 128; s; s >>= 1) {
        if (t < s) { sl[t] += sl[t + s]; sk[t] += sk[t + s]; sn[t] += sn[t + s]; }
        __syncthreads();
    }
    if (t == 0) {
        dout[0] = sl[0] / (float)B_N;
        const float kl = (sn[0] > 0.f) ? (sk[0] / fmaxf(sn[0], 1.f)) : 0.f;
        dout[1] = kl * (TEMP * TEMP) * 3.0f;
    }
}

extern "C" void kernel_launch(void* const* d_in, const int* in_sizes, int n_in,
                              void* d_out, int out_size, void* d_ws, size_t ws_size,
                              hipStream_t stream) {
    const int*   target = (const int*)  d_in[1];
    const float* cosf   = (const float*)d_in[2];
    const float* oldp   = (const float*)d_in[3];
    const float* e1     = (const float*)d_in[4];
    const float* e2     = (const float*)d_in[5];
    const float* e3     = (const float*)d_in[6];
    const float* outp   = (const float*)d_in[7];
    const float* prior  = (const float*)d_in[8];

    float* ws = (float*)d_ws;
    // per-row partials (zeroed each launch)
    float* S1 = ws;                       // [65536]
    float* S2 = S1 + B_N;
    float* S3 = S2 + B_N;
    float* DT = S3 + B_N;
    float* ZT = DT + B_N;
    float* ZS = ZT + B_N;
    float* DD = ZS + B_N;
    unsigned long long* KEY = (unsigned long long*)(DD + B_N);   // [65536] u64, 8B-aligned
    float* after = (float*)(KEY + B_N);
    float* sm   = after;                  // [10000]
    float* w2   = sm + 10000;             // [104]
    float* w3   = w2 + 104;
    float* Ht   = w3 + 104;
    int*   cnts = (int*)(Ht + 104);       // [104]
    float* pl   = (float*)(cnts + 104);   // [256]
    float* pk   = pl + 256;
    float* pn   = pk + 256;

    // zero S1..KEY (7 f32 arrays + 1 u64 array = 9*B_N floats) and cnts
    hipMemsetAsync(S1, 0, (size_t)9 * B_N * sizeof(float), stream);
    hipMemsetAsync(cnts, 0, 104 * sizeof(int), stream);

    prep_k<<<261, 256, 0, stream>>>(cosf, prior, target, sm, w2, w3, Ht, cnts);
    ce_k<<<CBLK, CTPB, 0, stream>>>(e1, e2, e3, target, sm, w2, w3, Ht, S1, S2, S3, DT);
    ts_k<<<CBLK, CTPB, 0, stream>>>(target, oldp, outp, cnts, (float*)d_out, ZT, ZS, DD, KEY);
    rf_k<<<B_N / 256, 256, 0, stream>>>(target, S1, S2, S3, DT, ZT, ZS, DD, KEY, pl, pk, pn);
    f2_k<<<1, 256, 0, stream>>>(pl, pk, pn, (float*)d_out);
}

// Round 11
// 46.766 us; speedup vs baseline: 2.2166x; 2.2166x over previous
//
#include <hip/hip_runtime.h>
#include <math.h>

#define B_N 65536
#define C_N 100
constexpr float ALPHA = 0.01f;
constexpr float TAU   = 2.0f;
constexpr float TEMP  = 2.0f;
constexpr float EPSF  = 1e-9f;
constexpr float NEG_SENT = -1.0e30f;   // sentinel: exp -> 0, finite

typedef float v2f __attribute__((ext_vector_type(2)));

// ---------------- DPP reduction helpers (VALU-only) ----------------
// After rowsum32, all lanes with (lane&31)>=16 hold the 32-group total.
template<int CTRL>
__device__ __forceinline__ float fadd_dpp(float x) {
    return x + __int_as_float(__builtin_amdgcn_update_dpp(
        0, __float_as_int(x), CTRL, 0xF, 0xF, true));
}
__device__ __forceinline__ float rowsum32(float x) {
    x = fadd_dpp<0xB1>(x);    // quad_perm xor1
    x = fadd_dpp<0x4E>(x);    // quad_perm xor2
    x = fadd_dpp<0x124>(x);   // row_ror:4
    x = fadd_dpp<0x128>(x);   // row_ror:8
    x = fadd_dpp<0x142>(x);   // row_bcast15
    return x;
}
template<int CTRL>
__device__ __forceinline__ void amax_dpp(unsigned &hi, unsigned &lo) {
    const unsigned yh = (unsigned)__builtin_amdgcn_update_dpp(0, (int)hi, CTRL, 0xF, 0xF, true);
    const unsigned yl = (unsigned)__builtin_amdgcn_update_dpp(0, (int)lo, CTRL, 0xF, 0xF, true);
    const bool take = (yh > hi) || (yh == hi && yl > lo);
    hi = take ? yh : hi;
    lo = take ? yl : lo;
}
__device__ __forceinline__ void rowamax32(unsigned &hi, unsigned &lo) {
    amax_dpp<0xB1>(hi, lo);
    amax_dpp<0x4E>(hi, lo);
    amax_dpp<0x124>(hi, lo);
    amax_dpp<0x128>(hi, lo);
    amax_dpp<0x142>(hi, lo);
}

__device__ __forceinline__ float wsum(float v) {
    #pragma unroll
    for (int o = 32; o; o >>= 1) v += __shfl_xor(v, o);
    return v;
}

// ---------- prep: bincount (0-255) + prior tables (256) + cos softmax (257-260) ----------
__global__ void prep_k(const float* __restrict__ cosf, const float* __restrict__ prior,
                       const int* __restrict__ target,
                       float* __restrict__ sm, float* __restrict__ w2,
                       float* __restrict__ w3, float* __restrict__ Ht,
                       int* __restrict__ counts) {
    const int b = blockIdx.x;
    if (b < 256) {
        __shared__ int h[C_N];
        for (int i = threadIdx.x; i < C_N; i += blockDim.x) h[i] = 0;
        __syncthreads();
        const int gid = b * blockDim.x + threadIdx.x;
        const int stride = 256 * blockDim.x;
        for (int i = gid; i < B_N; i += stride) atomicAdd(&h[target[i]], 1);
        __syncthreads();
        for (int i = threadIdx.x; i < C_N; i += blockDim.x)
            if (h[i]) atomicAdd(&counts[i], h[i]);
    } else if (b == 256) {
        __shared__ float sp[C_N];
        __shared__ float val[C_N];
        const int t = threadIdx.x;
        if (t < C_N) sp[t] = prior[t];
        __syncthreads();
        int rank = 0;
        float lpi = 0.f, pi = 0.f;
        if (t < C_N) {
            pi = sp[t];
            for (int j = 0; j < C_N; ++j) {
                const float pj = sp[j];
                rank += (pj < pi) || (pj == pi && j < t);   // stable argsort rank
            }
            val[rank] = pi;
            lpi = __logf(pi + EPSF);
        }
        __syncthreads();
        if (t < C_N) {
            const float inv = val[C_N - 1 - rank];
            const float c3v = lpi - TAU * __logf(inv + EPSF);
            w2[t] = pi + EPSF;          // exp(e2+lp) = w2*exp(e2)
            w3[t] = __expf(c3v);        // exp(e3+c3) = w3*exp(e3)
            Ht[t] = lpi + c3v;          // lp+c3, for the label dot
        }
    } else {
        const int gw = (b - 257) * 4 + (threadIdx.x >> 6);   // 0..15
        const int lane = threadIdx.x & 63;
        for (int row = gw; row < C_N; row += 16) {
            const float* rp = cosf + row * C_N;
            const float v0 = rp[lane];
            const bool has1 = (lane + 64) < C_N;
            const float v1 = has1 ? rp[lane + 64] : -INFINITY;
            float m = fmaxf(v0, v1);
            #pragma unroll
            for (int o = 32; o; o >>= 1) m = fmaxf(m, __shfl_xor(m, o));
            const float e0 = __expf(v0 - m);
            const float e1 = has1 ? __expf(v1 - m) : 0.f;
            const float s = wsum(e0 + e1);
            const float is = 1.0f / s;
            sm[row * C_N + lane] = e0 * is;
            if (has1) sm[row * C_N + lane + 64] = e1 * is;
        }
    }
}

// ---------- main: role-interleaved blocks (even=CE, odd=KL), nt stores, bucket partials ----------
#define HBLK 4096
#define NBLK (2 * HBLK)

__launch_bounds__(256, 8)
__global__ void main_k(const int* __restrict__ target,
                       const float* __restrict__ e1p, const float* __restrict__ e2p,
                       const float* __restrict__ e3p, const float* __restrict__ opp,
                       const float* __restrict__ outp,
                       const float* __restrict__ sm, const float* __restrict__ w2p,
                       const float* __restrict__ w3p, const float* __restrict__ Hp,
                       const int* __restrict__ counts,
                       float* __restrict__ dout,
                       float* __restrict__ pl, float* __restrict__ pk, float* __restrict__ pn) {
    const int lane = threadIdx.x & 63;
    const int gl   = lane & 31;
    const int half = lane >> 5;
    const int wslot = threadIdx.x >> 6;
    const bool act = gl < 25;
    const int c0 = 4 * gl;
    const bool own = (gl == 16);
    __shared__ float bl[4], bk[4], bn[4];
    const int role = blockIdx.x & 1;
    const int j    = blockIdx.x >> 1;
    const int bucket = blockIdx.x & 255;

    if (role == 0) {
        // ================= CE role: e1,e2,e3 + sm gather -> loss partial =================
        const int gw = j * 4 + wslot;
        const int rowA = 4 * gw + half;
        const int rowB = 4 * gw + 2 + half;
        const int tgtA = target[rowA];
        const int tgtB = target[rowB];
        const int baseA = rowA * C_N;
        const int baseB = rowB * C_N;

        float4 W2 = make_float4(0,0,0,0), W3 = make_float4(0,0,0,0), HH = make_float4(0,0,0,0);
        float4 E1A, E2A, E3A, E1B, E2B, E3B, SMA, SMB;
        E1A = E2A = E3A = E1B = E2B = E3B = make_float4(NEG_SENT, NEG_SENT, NEG_SENT, NEG_SENT);
        SMA = SMB = make_float4(0,0,0,0);
        if (act) {
            W2  = *(const float4*)(w2p + c0);
            W3  = *(const float4*)(w3p + c0);
            HH  = *(const float4*)(Hp + c0);
            E1A = *(const float4*)(e1p + baseA + c0);
            E1B = *(const float4*)(e1p + baseB + c0);
            E2A = *(const float4*)(e2p + baseA + c0);
            E2B = *(const float4*)(e2p + baseB + c0);
            E3A = *(const float4*)(e3p + baseA + c0);
            E3B = *(const float4*)(e3p + baseB + c0);
            SMA = *(const float4*)(sm + tgtA * C_N + c0);
            SMB = *(const float4*)(sm + tgtB * C_N + c0);
        }

        const float laA0 = (1.0f - ALPHA) * (c0     == tgtA) + ALPHA * SMA.x;
        const float laA1 = (1.0f - ALPHA) * (c0 + 1 == tgtA) + ALPHA * SMA.y;
        const float laA2 = (1.0f - ALPHA) * (c0 + 2 == tgtA) + ALPHA * SMA.z;
        const float laA3 = (1.0f - ALPHA) * (c0 + 3 == tgtA) + ALPHA * SMA.w;
        float s1A = __expf(E1A.x) + __expf(E1A.y) + __expf(E1A.z) + __expf(E1A.w);
        float s2A = W2.x * __expf(E2A.x) + W2.y * __expf(E2A.y)
                  + W2.z * __expf(E2A.z) + W2.w * __expf(E2A.w);
        float s3A = W3.x * __expf(E3A.x) + W3.y * __expf(E3A.y)
                  + W3.z * __expf(E3A.z) + W3.w * __expf(E3A.w);
        float dtA = laA0 * (E1A.x + E2A.x + E3A.x + HH.x)
                  + laA1 * (E1A.y + E2A.y + E3A.y + HH.y)
                  + laA2 * (E1A.z + E2A.z + E3A.z + HH.z)
                  + laA3 * (E1A.w + E2A.w + E3A.w + HH.w);
        const float laB0 = (1.0f - ALPHA) * (c0     == tgtB) + ALPHA * SMB.x;
        const float laB1 = (1.0f - ALPHA) * (c0 + 1 == tgtB) + ALPHA * SMB.y;
        const float laB2 = (1.0f - ALPHA) * (c0 + 2 == tgtB) + ALPHA * SMB.z;
        const float laB3 = (1.0f - ALPHA) * (c0 + 3 == tgtB) + ALPHA * SMB.w;
        float s1B = __expf(E1B.x) + __expf(E1B.y) + __expf(E1B.z) + __expf(E1B.w);
        float s2B = W2.x * __expf(E2B.x) + W2.y * __expf(E2B.y)
                  + W2.z * __expf(E2B.z) + W2.w * __expf(E2B.w);
        float s3B = W3.x * __expf(E3B.x) + W3.y * __expf(E3B.y)
                  + W3.z * __expf(E3B.z) + W3.w * __expf(E3B.w);
        float dtB = laB0 * (E1B.x + E2B.x + E3B.x + HH.x)
                  + laB1 * (E1B.y + E2B.y + E3B.y + HH.y)
                  + laB2 * (E1B.z + E2B.z + E3B.z + HH.z)
                  + laB3 * (E1B.w + E2B.w + E3B.w + HH.w);

        s1A = rowsum32(s1A);  s1B = rowsum32(s1B);
        s2A = rowsum32(s2A);  s2B = rowsum32(s2B);
        s3A = rowsum32(s3A);  s3B = rowsum32(s3B);
        dtA = rowsum32(dtA);  dtB = rowsum32(dtB);

        const float ceA = __logf(s1A * s2A * s3A) - dtA;
        const float ceB = __logf(s1B * s2B * s3B) - dtB;
        float lossAcc = own ? (ceA + ceB) : 0.f;
        const float lossW = __shfl(lossAcc, 16) + __shfl(lossAcc, 48);
        if (lane == 0) bl[wslot] = lossW;
        __syncthreads();
        if (threadIdx.x == 0)
            atomicAdd(&pl[bucket], bl[0] + bl[1] + bl[2] + bl[3]);
    } else {
        // ================= KL role: old_pred,output -> kl partial + dout rows =================
        const int gw = j * 4 + wslot;
        const int rowA = 4 * gw + half;
        const int rowB = 4 * gw + 2 + half;
        const int tgtA = target[rowA];
        const int tgtB = target[rowB];
        const int baseA = rowA * C_N;
        const int baseB = rowB * C_N;

        float4 OPA, OUA, OPB, OUB;
        OPA = OUA = OPB = OUB = make_float4(NEG_SENT, NEG_SENT, NEG_SENT, NEG_SENT);
        if (act) {
            OPA = *(const float4*)(opp + baseA + c0);
            OPB = *(const float4*)(opp + baseB + c0);
            OUA = *(const float4*)(outp + baseA + c0);
            OUB = *(const float4*)(outp + baseB + c0);
        }
        const float rcA = 1.0f / (float)counts[tgtA];
        const float rcB = 1.0f / (float)counts[tgtB];

        // pair A
        const float aA0 = OPA.x * 0.5f, aA1 = OPA.y * 0.5f, aA2 = OPA.z * 0.5f, aA3 = OPA.w * 0.5f;
        const float pA0 = __expf(aA0), pA1 = __expf(aA1), pA2 = __expf(aA2), pA3 = __expf(aA3);
        float ztA = pA0 + pA1 + pA2 + pA3;
        float bvA = OPA.x; int biA = c0;
        if (OPA.y > bvA) { bvA = OPA.y; biA = c0 + 1; }
        if (OPA.z > bvA) { bvA = OPA.z; biA = c0 + 2; }
        if (OPA.w > bvA) { bvA = OPA.w; biA = c0 + 3; }
        unsigned bbA = __float_as_uint(bvA);
        bbA = ((int)bbA < 0) ? ~bbA : (bbA | 0x80000000u);
        unsigned khiA = bbA, kloA = (unsigned)~biA;
        const float esA0 = OUA.x * rcA, esA1 = OUA.y * rcA, esA2 = OUA.z * rcA, esA3 = OUA.w * rcA;
        const float xA0 = esA0 * 0.5f, xA1 = esA1 * 0.5f, xA2 = esA2 * 0.5f, xA3 = esA3 * 0.5f;
        float zsA = __expf(xA0) + __expf(xA1) + __expf(xA2) + __expf(xA3);
        float DA  = pA0 * (aA0 - xA0) + pA1 * (aA1 - xA1) + pA2 * (aA2 - xA2) + pA3 * (aA3 - xA3);
        if (act) {
            v2f w0 = { esA0, esA1 };
            v2f w1 = { esA2, esA3 };
            __builtin_nontemporal_store(w0, (v2f*)(dout + 2 + baseA + c0));
            __builtin_nontemporal_store(w1, (v2f*)(dout + 2 + baseA + c0 + 2));
        }
        // pair B
        const float aB0 = OPB.x * 0.5f, aB1 = OPB.y * 0.5f, aB2 = OPB.z * 0.5f, aB3 = OPB.w * 0.5f;
        const float pB0 = __expf(aB0), pB1 = __expf(aB1), pB2 = __expf(aB2), pB3 = __expf(aB3);
        float ztB = pB0 + pB1 + pB2 + pB3;
        float bvB = OPB.x; int biB = c0;
        if (OPB.y > bvB) { bvB = OPB.y; biB = c0 + 1; }
        if (OPB.z > bvB) { bvB = OPB.z; biB = c0 + 2; }
        if (OPB.w > bvB) { bvB = OPB.w; biB = c0 + 3; }
        unsigned bbB = __float_as_uint(bvB);
        bbB = ((int)bbB < 0) ? ~bbB : (bbB | 0x80000000u);
        unsigned khiB = bbB, kloB = (unsigned)~biB;
        const float esB0 = OUB.x * rcB, esB1 = OUB.y * rcB, esB2 = OUB.z * rcB, esB3 = OUB.w * rcB;
        const float xB0 = esB0 * 0.5f, xB1 = esB1 * 0.5f, xB2 = esB2 * 0.5f, xB3 = esB3 * 0.5f;
        float zsB = __expf(xB0) + __expf(xB1) + __expf(xB2) + __expf(xB3);
        float DB  = pB0 * (aB0 - xB0) + pB1 * (aB1 - xB1) + pB2 * (aB2 - xB2) + pB3 * (aB3 - xB3);
        if (act) {
            v2f w0 = { esB0, esB1 };
            v2f w1 = { esB2, esB3 };
            __builtin_nontemporal_store(w0, (v2f*)(dout + 2 + baseB + c0));
            __builtin_nontemporal_store(w1, (v2f*)(dout + 2 + baseB + c0 + 2));
        }

        ztA = rowsum32(ztA);  ztB = rowsum32(ztB);
        zsA = rowsum32(zsA);  zsB = rowsum32(zsB);
        DA  = rowsum32(DA);   DB  = rowsum32(DB);
        rowamax32(khiA, kloA);
        rowamax32(khiB, kloB);

        const int miA = (int)~kloA;
        const int miB = (int)~kloB;
        const float rztA = 1.0f / ztA, rztB = 1.0f / ztB;
        const float klvA = DA * rztA + __logf(zsA * rztA);
        const float klvB = DB * rztB + __logf(zsB * rztB);
        const bool selA = own && (miA == tgtA);
        const bool selB = own && (miB == tgtB);
        float klAcc = (selA ? klvA : 0.f) + (selB ? klvB : 0.f);
        float nAcc  = (selA ? 1.f : 0.f) + (selB ? 1.f : 0.f);
        const float klW = __shfl(klAcc, 16) + __shfl(klAcc, 48);
        const float nW  = __shfl(nAcc, 16) + __shfl(nAcc, 48);
        if (lane == 0) { bk[wslot] = klW; bn[wslot] = nW; }
        __syncthreads();
        if (threadIdx.x == 0) {
            atomicAdd(&pk[bucket], bk[0] + bk[1] + bk[2] + bk[3]);
            atomicAdd(&pn[bucket], bn[0] + bn[1] + bn[2] + bn[3]);
        }
    }
}

// ---------- final: reduce 256 buckets ----------
__global__ void final_k(const float* __restrict__ pl, const float* __restrict__ pk,
                        const float* __restrict__ pn, float* __restrict__ dout) {
    __shared__ float sl[256], sk[256], sn[256];
    const int t = threadIdx.x;
    sl[t] = pl[t]; sk[t] = pk[t]; sn[t] = pn[t];
    __syncthreads();
    for (int s = 128; s; s >>= 1) {
        if (t < s) { sl[t] += sl[t + s]; sk[t] += sk[t + s]; sn[t] += sn[t + s]; }
        __syncthreads();
    }
    if (t == 0) {
        dout[0] = sl[0] / (float)B_N;
        const float kl = (sn[0] > 0.f) ? (sk[0] / fmaxf(sn[0], 1.f)) : 0.f;
        dout[1] = kl * (TEMP * TEMP) * 3.0f;
    }
}

extern "C" void kernel_launch(void* const* d_in, const int* in_sizes, int n_in,
                              void* d_out, int out_size, void* d_ws, size_t ws_size,
                              hipStream_t stream) {
    const int*   target = (const int*)  d_in[1];
    const float* cosf   = (const float*)d_in[2];
    const float* oldp   = (const float*)d_in[3];
    const float* e1     = (const float*)d_in[4];
    const float* e2     = (const float*)d_in[5];
    const float* e3     = (const float*)d_in[6];
    const float* outp   = (const float*)d_in[7];
    const float* prior  = (const float*)d_in[8];

    float* ws    = (float*)d_ws;
    float* sm    = ws;                  // [10000] (+16 pad)
    float* w2    = ws + 10016;          // [104]
    float* w3    = ws + 10120;          // [104]
    float* Ht    = ws + 10224;          // [104]
    int*   cnts  = (int*)(ws + 10328);  // [104]
    float* pl    = ws + 10432;          // [256]
    float* pk    = pl + 256;            // [256]
    float* pn    = pk + 256;            // [256]

    // zero cnts + pl/pk/pn in one shot (contiguous: 104 ints + 768 floats)
    hipMemsetAsync(cnts, 0, (104 + 768) * sizeof(float), stream);
    prep_k<<<261, 256, 0, stream>>>(cosf, prior, target, sm, w2, w3, Ht, cnts);
    main_k<<<NBLK, 256, 0, stream>>>(target, e1, e2, e3, oldp, outp,
                                     sm, w2, w3, Ht, cnts, (float*)d_out, pl, pk, pn);
    final_k<<<1, 256, 0, stream>>>(pl, pk, pn, (float*)d_out);
}